// Round 4
// baseline (228.626 us; speedup 1.0000x reference)
//
#include <hip/hip_runtime.h>
#include <hip/hip_bf16.h>
#include <math.h>

// out[b,s,d] = x[b,s,d] + pe[s,d];  x: fp32 [8, 4096, 1024]
// pe[s,d] = sin(s * 10000^(-2d/1024)) if d even else cos(...)
//
// R1: batch-amortized pe → latency-bound, 97 us (VGPR=32 serialized 8 ld/st).
// R2: max-TLP, bad chain constants → fail (phase error ×4000 rad).
// R3: max-TLP + exact math → ~77 us, VALU-bound: 4 medium-range Payne-Hanek
//     sin/cos per STREAMED float4 doesn't hide under the ~30 us memory floor.
// R4: split. Kernel A materializes pe[S,D] (16 MB) in d_ws — transcendental
//     cost paid once (1M threads, ~5 us). Kernel B is a pure streaming add
//     (pe L3-resident across 8x batch reuse) — memory-bound by construction.

#define PE_D 1024
#define PE_S 4096
#define PE_B 8

// ---- Kernel A: pe[s,d] -> ws (fp32), 1M float4 threads ----
__global__ __launch_bounds__(256) void
pe_init_kernel(float* __restrict__ pe) {
    const int tid = blockIdx.x * blockDim.x + threadIdx.x;   // over S*D/4 = 1M
    const int d4  = tid & (PE_D / 4 - 1);
    const int s   = tid >> 8;
    const int d0  = d4 << 2;

    const float pos = (float)s;
    const float c = -0.025952563241307517f;                  // -2*log2(1e4)/1024

    float4 v;
    v.x = sinf(pos * exp2f(c * (float)(d0 + 0)));            // even -> sin
    v.y = cosf(pos * exp2f(c * (float)(d0 + 1)));            // odd  -> cos
    v.z = sinf(pos * exp2f(c * (float)(d0 + 2)));
    v.w = cosf(pos * exp2f(c * (float)(d0 + 3)));

    *(float4*)(pe + (size_t)tid * 4) = v;
}

// ---- Kernel B: out = x + pe (broadcast over batch), 8M float4 threads ----
__global__ __launch_bounds__(256) void
pe_add_kernel(const float* __restrict__ x, const float* __restrict__ pe,
              float* __restrict__ out) {
    const int tid = blockIdx.x * blockDim.x + threadIdx.x;   // over B*S*D/4 = 8M
    const int pidx = tid & (PE_S * PE_D / 4 - 1);            // (s,d4) within plane

    const float4 v = *(const float4*)(x + (size_t)tid * 4);
    const float4 p = *(const float4*)(pe + (size_t)pidx * 4);

    float4 r;
    r.x = v.x + p.x;
    r.y = v.y + p.y;
    r.z = v.z + p.z;
    r.w = v.w + p.w;
    *(float4*)(out + (size_t)tid * 4) = r;
}

// ---- Fallback (R3): fused recompute, used only if ws too small ----
__global__ __launch_bounds__(256) void
pe_fused_kernel(const float* __restrict__ x, float* __restrict__ out) {
    const int tid = blockIdx.x * blockDim.x + threadIdx.x;
    const int d4  = tid & (PE_D / 4 - 1);
    const int s   = (tid >> 8) & (PE_S - 1);
    const int d0  = d4 << 2;

    const size_t base = (size_t)tid * 4;
    const float4 v = *(const float4*)(x + base);

    const float pos = (float)s;
    const float c = -0.025952563241307517f;

    float4 pe;
    pe.x = sinf(pos * exp2f(c * (float)(d0 + 0)));
    pe.y = cosf(pos * exp2f(c * (float)(d0 + 1)));
    pe.z = sinf(pos * exp2f(c * (float)(d0 + 2)));
    pe.w = cosf(pos * exp2f(c * (float)(d0 + 3)));

    float4 r;
    r.x = v.x + pe.x;
    r.y = v.y + pe.y;
    r.z = v.z + pe.z;
    r.w = v.w + pe.w;
    *(float4*)(out + base) = r;
}

extern "C" void kernel_launch(void* const* d_in, const int* in_sizes, int n_in,
                              void* d_out, int out_size, void* d_ws, size_t ws_size,
                              hipStream_t stream) {
    const float* x = (const float*)d_in[0];
    float* out     = (float*)d_out;

    const size_t pe_bytes = (size_t)PE_S * PE_D * sizeof(float);   // 16 MiB

    if (ws_size >= pe_bytes) {
        float* pe = (float*)d_ws;
        const int nA = PE_S * PE_D / 4;                      // 1,048,576
        pe_init_kernel<<<nA / 256, 256, 0, stream>>>(pe);
        const int nB = PE_B * PE_S * PE_D / 4;               // 8,388,608
        pe_add_kernel<<<nB / 256, 256, 0, stream>>>(x, pe, out);
    } else {
        const int n = PE_B * PE_S * PE_D / 4;
        pe_fused_kernel<<<n / 256, 256, 0, stream>>>(x, out);
    }
}

// Round 5
// 221.503 us; speedup vs baseline: 1.0322x; 1.0322x over previous
//
#include <hip/hip_runtime.h>
#include <hip/hip_bf16.h>
#include <math.h>

// out[b,s,d] = x[b,s,d] + pe[s,d];  x: fp32 [8, 4096, 1024]
// pe[s,d] = sin(s * 10000^(-2d/1024)) if d even else cos(...)
//
// R1: batch-amortized pe → latency-bound, 97 us (VGPR=32 serialized ld/st).
// R2: max-TLP, 5-sig-fig chain constants → fail (1e-5 rel × 4000 rad phase).
// R3: max-TLP + libm sinf/cosf → ~77 us. Not memory-bound: libm large-arg
//     (up to 4095 rad) reduction is ~60+ insts with serial chains per call.
// R4: pe materialized in ws → ~85 us. Split overhead > recompute cost.
// R5: hardware v_sin/v_cos (revolutions). Fold 1/2pi into the exponent:
//     r = fract(s * exp2(c*d - log2(2pi))), sin(2pi*r) via v_sin_f32.
//     5 VALU insts/element → ~4 us VALU, hidden under ~35 us memory floor.

#define PE_D 1024
#define PE_S 4096
#define PE_B 8

__global__ __launch_bounds__(256) void
PositionalEncoderModule_48455821033878_kernel(const float* __restrict__ x,
                                              float* __restrict__ out) {
    const int tid = blockIdx.x * blockDim.x + threadIdx.x;   // over B*S*D/4 = 8M
    const int d4  = tid & (PE_D / 4 - 1);                    // float4 index in row
    const int s   = (tid >> 8) & (PE_S - 1);                 // seq position
    const int d0  = d4 << 2;                                 // even

    // Issue the load first; pe math overlaps the wait.
    const size_t base = (size_t)tid * 4;
    const float4 v = *(const float4*)(x + base);

    const float pos = (float)s;
    // g(d) = 10000^(-2d/1024) / (2pi) = exp2(c*d + K)
    //   c = -2*log2(1e4)/1024, K = -log2(2pi)
    const float c = -0.025952563241307517f;
    const float K = -2.6514961294723187f;

    // r_i = fract(pos * g(d0+i)) in revolutions; v_sin_f32(r) = sin(2pi*r)
    const float g0 = __builtin_amdgcn_exp2f(fmaf(c, (float)(d0 + 0), K));
    const float g1 = __builtin_amdgcn_exp2f(fmaf(c, (float)(d0 + 1), K));
    const float g2 = __builtin_amdgcn_exp2f(fmaf(c, (float)(d0 + 2), K));
    const float g3 = __builtin_amdgcn_exp2f(fmaf(c, (float)(d0 + 3), K));

    const float r0 = __builtin_amdgcn_fractf(pos * g0);
    const float r1 = __builtin_amdgcn_fractf(pos * g1);
    const float r2 = __builtin_amdgcn_fractf(pos * g2);
    const float r3 = __builtin_amdgcn_fractf(pos * g3);

    float4 pe;
    pe.x = __builtin_amdgcn_sinf(r0);                        // even -> sin
    pe.y = __builtin_amdgcn_cosf(r1);                        // odd  -> cos
    pe.z = __builtin_amdgcn_sinf(r2);
    pe.w = __builtin_amdgcn_cosf(r3);

    float4 r;
    r.x = v.x + pe.x;
    r.y = v.y + pe.y;
    r.z = v.z + pe.z;
    r.w = v.w + pe.w;
    *(float4*)(out + base) = r;
}

extern "C" void kernel_launch(void* const* d_in, const int* in_sizes, int n_in,
                              void* d_out, int out_size, void* d_ws, size_t ws_size,
                              hipStream_t stream) {
    const float* x = (const float*)d_in[0];
    float* out     = (float*)d_out;

    const int n_threads = PE_B * PE_S * PE_D / 4;            // 8,388,608
    const int block = 256;
    const int grid  = n_threads / block;                     // 32768

    PositionalEncoderModule_48455821033878_kernel<<<grid, block, 0, stream>>>(x, out);
}